// Round 1
// baseline (72.828 us; speedup 1.0000x reference)
//
#include <hip/hip_runtime.h>
#include <hip/hip_bf16.h>

typedef float fx4 __attribute__((ext_vector_type(4)));
typedef short i16x8 __attribute__((ext_vector_type(8)));
typedef unsigned short u16;

#define NEG_INF_F (-9.0e15f)

__device__ inline u16 f2bf(float v){
  __hip_bfloat16 h = __float2bfloat16(v);
  return *reinterpret_cast<u16*>(&h);
}

// ---------------------------------------------------------------------------
// Kernel 1: Wh = x @ W (fp32), f1 = Wh@a1, f2 = Wh@a2 (fp32),
// WhT stored bf16 as [bt][o][j]  (MFMA B-operand friendly layout).
// grid (2, 96), 256 threads; thread = one node n.
// ---------------------------------------------------------------------------
__global__ __launch_bounds__(256) void gat_prep(
    const float* __restrict__ input,   // (8,64,12,512)
    const float* __restrict__ W,       // (64,64)
    const float* __restrict__ Avec,    // (128,1)
    u16*   __restrict__ whT,           // (96,64,512) bf16
    float* __restrict__ f1w,           // (96,512)
    float* __restrict__ f2w)           // (96,512)
{
  __shared__ float Wl[64*64];
  __shared__ float Al[128];
  const int tid = threadIdx.x;
  const int bt  = blockIdx.y;
  const int b   = bt / 12, t = bt % 12;
  const int n   = blockIdx.x * 256 + tid;

  {
    const fx4* src = (const fx4*)W;
    fx4* dst = (fx4*)Wl;
    #pragma unroll
    for (int i = 0; i < 4; ++i) dst[tid + 256*i] = src[tid + 256*i];
    if (tid < 32) ((fx4*)Al)[tid] = ((const fx4*)Avec)[tid];
  }
  __syncthreads();

  // x[b, f, t, n], stride between f = 12*512 = 6144
  const float* xp = input + ((size_t)b*64*12 + t) * 512 + n;

  fx4 acc[16];
  #pragma unroll
  for (int i = 0; i < 16; ++i) acc[i] = (fx4){0.f,0.f,0.f,0.f};

  #pragma unroll 8
  for (int f = 0; f < 64; ++f) {
    float xv = xp[(size_t)f * 6144];
    const fx4* wr = (const fx4*)(Wl + f*64);
    #pragma unroll
    for (int o4 = 0; o4 < 16; ++o4) acc[o4] += xv * wr[o4];
  }

  float s1 = 0.f, s2 = 0.f;
  #pragma unroll
  for (int o4 = 0; o4 < 16; ++o4) {
    fx4 v  = acc[o4];
    fx4 w1 = ((const fx4*)Al)[o4];
    fx4 w2 = ((const fx4*)Al)[o4 + 16];
    s1 += v[0]*w1[0] + v[1]*w1[1] + v[2]*w1[2] + v[3]*w1[3];
    s2 += v[0]*w2[0] + v[1]*w2[1] + v[2]*w2[2] + v[3]*w2[3];
  }
  f1w[bt*512 + n] = s1;
  f2w[bt*512 + n] = s2;

  u16* wp = whT + (size_t)bt*64*512 + n;
  #pragma unroll
  for (int o4 = 0; o4 < 16; ++o4) {
    #pragma unroll
    for (int c = 0; c < 4; ++c)
      wp[(size_t)(o4*4 + c) * 512] = f2bf(acc[o4][c]);
  }
}

// ---------------------------------------------------------------------------
// Kernel 2: masked softmax (phase A) + PV via MFMA (phase B) + ELU.
// grid (16, 96), 128 threads (2 waves). Wave w handles 16 rows.
// LDS: f2 (2KB) + f1 (128B) + attn bf16 [32][512] XOR-swizzled (32KB).
// ---------------------------------------------------------------------------
__global__ __launch_bounds__(128) void gat_attn(
    const int*   __restrict__ adj,   // (96,512,512)
    const u16*   __restrict__ whT,   // (96,64,512) bf16
    const float* __restrict__ f1w,
    const float* __restrict__ f2w,
    float*       __restrict__ out)   // (96,512,64)
{
  __shared__ float f2l[512];
  __shared__ float f1l[32];
  __shared__ u16   attnl[32*512];

  const int tid = threadIdx.x;
  const int l   = tid & 63;
  const int w   = tid >> 6;
  const int bt  = blockIdx.y;
  const int it  = blockIdx.x;

  ((fx4*)f2l)[tid] = ((const fx4*)(f2w + bt*512))[tid];
  if (tid < 32) f1l[tid] = f1w[bt*512 + it*32 + tid];
  __syncthreads();

  // ---------------- phase A: masked softmax rows -> attn (bf16, LDS) -------
  const int R0     = w * 16;          // local row base for this wave
  const int row_g0 = it*32 + R0;      // global row base
  const int4* adj4 = (const int4*)(adj + (size_t)bt*512*512);

  int4 pre[4][2];                     // 4-row prefetch pipeline
  #pragma unroll
  for (int p = 0; p < 4; ++p) {
    const int4* ar = adj4 + (size_t)(row_g0 + p) * 128;
    pre[p][0] = ar[l];
    pre[p][1] = ar[64 + l];
  }

  #pragma unroll
  for (int r = 0; r < 16; ++r) {
    int4 c0 = pre[r & 3][0];
    int4 c1 = pre[r & 3][1];
    if (r + 4 < 16) {
      const int4* ar = adj4 + (size_t)(row_g0 + r + 4) * 128;
      pre[r & 3][0] = ar[l];
      pre[r & 3][1] = ar[64 + l];
    }
    const float f1v = f1l[R0 + r];
    fx4 f20 = ((const fx4*)f2l)[l];        // j = 4l .. 4l+3
    fx4 f21 = ((const fx4*)f2l)[64 + l];   // j = 256+4l ..
    float e[8], m = NEG_INF_F;
#define GAT_E(idx, cc, ff) { float s = f1v + (ff); float lr = s > 0.f ? s : 0.2f*s; \
                             e[idx] = ((cc) > 0) ? lr : NEG_INF_F; m = fmaxf(m, e[idx]); }
    GAT_E(0, c0.x, f20[0]) GAT_E(1, c0.y, f20[1]) GAT_E(2, c0.z, f20[2]) GAT_E(3, c0.w, f20[3])
    GAT_E(4, c1.x, f21[0]) GAT_E(5, c1.y, f21[1]) GAT_E(6, c1.z, f21[2]) GAT_E(7, c1.w, f21[3])
#undef GAT_E
    #pragma unroll
    for (int off = 32; off >= 1; off >>= 1) m = fmaxf(m, __shfl_xor(m, off));
    float sum = 0.f;
    #pragma unroll
    for (int i = 0; i < 8; ++i) { e[i] = __expf(e[i] - m); sum += e[i]; }
    #pragma unroll
    for (int off = 32; off >= 1; off >>= 1) sum += __shfl_xor(sum, off);
    const float rs = 1.0f / sum;

    const int rowR = R0 + r;
    const unsigned swz = (unsigned)((rowR & 7) << 4);
    char* base = (char*)attnl + rowR * 1024;
    ushort4 pk0, pk1;
    pk0.x = f2bf(e[0]*rs); pk0.y = f2bf(e[1]*rs); pk0.z = f2bf(e[2]*rs); pk0.w = f2bf(e[3]*rs);
    pk1.x = f2bf(e[4]*rs); pk1.y = f2bf(e[5]*rs); pk1.z = f2bf(e[6]*rs); pk1.w = f2bf(e[7]*rs);
    *(ushort4*)(base + (((unsigned)(      8*l)) ^ swz)) = pk0;
    *(ushort4*)(base + (((unsigned)(512 + 8*l)) ^ swz)) = pk1;
  }

  __syncthreads();

  // ---------------- phase B: h = attn @ Wh via MFMA, fused ELU -------------
  const int r = l & 15, q = l >> 4;
  const unsigned swzB = (unsigned)((r & 7) << 4);
  const char* aBase = (const char*)attnl + (R0 + r) * 1024;
  const u16*  wb    = whT + (size_t)bt*64*512;
  fx4 acc0 = {0,0,0,0}, acc1 = {0,0,0,0}, acc2 = {0,0,0,0}, acc3 = {0,0,0,0};

  #pragma unroll
  for (int jt = 0; jt < 512; jt += 32) {
    // A: attn[R0+r][jt + 8q .. +7]   (16B swizzled LDS read)
    i16x8 af = *(const i16x8*)(aBase + (((unsigned)(jt*2 + q*16)) ^ swzB));
    // B: WhT[o = ot*16+r][jt + 8q .. +7]  (16B global reads, L1/L2-hot)
    const u16* bp = wb + (size_t)r*512 + jt + 8*q;
    i16x8 b0 = *(const i16x8*)(bp);
    i16x8 b1 = *(const i16x8*)(bp + 16*512);
    i16x8 b2 = *(const i16x8*)(bp + 32*512);
    i16x8 b3 = *(const i16x8*)(bp + 48*512);
    acc0 = __builtin_amdgcn_mfma_f32_16x16x32_bf16(af, b0, acc0, 0, 0, 0);
    acc1 = __builtin_amdgcn_mfma_f32_16x16x32_bf16(af, b1, acc1, 0, 0, 0);
    acc2 = __builtin_amdgcn_mfma_f32_16x16x32_bf16(af, b2, acc2, 0, 0, 0);
    acc3 = __builtin_amdgcn_mfma_f32_16x16x32_bf16(af, b3, acc3, 0, 0, 0);
  }

  // C/D layout: col = l&15 (=o within tile), row = q*4 + rr
  float* op = out + ((size_t)bt*512 + it*32 + R0) * 64;
#define GAT_ST(accv, ot) { \
    _Pragma("unroll") \
    for (int rr = 0; rr < 4; ++rr) { \
      float v = (accv)[rr]; \
      v = v > 0.f ? v : expm1f(v); \
      op[(q*4 + rr)*64 + (ot)*16 + r] = v; \
    } }
  GAT_ST(acc0, 0) GAT_ST(acc1, 1) GAT_ST(acc2, 2) GAT_ST(acc3, 3)
#undef GAT_ST
}

// ---------------------------------------------------------------------------
extern "C" void kernel_launch(void* const* d_in, const int* in_sizes, int n_in,
                              void* d_out, int out_size, void* d_ws, size_t ws_size,
                              hipStream_t stream) {
  const float* input = (const float*)d_in[0];   // (8,64,12,512) f32
  const int*   adj   = (const int*)  d_in[1];   // (8,12,512,512) i32
  const float* W     = (const float*)d_in[2];   // (64,64) f32
  const float* Avec  = (const float*)d_in[3];   // (128,1) f32
  float* out = (float*)d_out;

  // workspace layout: whT bf16 (6,291,456 B) | f1 (196,608 B) | f2 (196,608 B)
  char* ws = (char*)d_ws;
  u16*   whT = (u16*)ws;
  float* f1w = (float*)(ws + 6291456);
  float* f2w = (float*)(ws + 6291456 + 196608);

  gat_prep<<<dim3(2, 96), 256, 0, stream>>>(input, W, Avec, whT, f1w, f2w);
  gat_attn<<<dim3(16, 96), 128, 0, stream>>>(adj, whT, f1w, f2w, out);
}

// Round 3
// 62.295 us; speedup vs baseline: 1.1691x; 1.1691x over previous
//
#include <hip/hip_runtime.h>
#include <hip/hip_bf16.h>

typedef float fx4 __attribute__((ext_vector_type(4)));
typedef short i16x8 __attribute__((ext_vector_type(8)));
typedef unsigned short u16;

#define NEG_INF_F (-9.0e15f)

__device__ inline u16 f2bf(float v){
  __hip_bfloat16 h = __float2bfloat16(v);
  return *reinterpret_cast<u16*>(&h);
}

// ---------------------------------------------------------------------------
// Kernel 1: Wh = x @ W (fp32), f1 = Wh@a1, f2 = Wh@a2 (fp32),
// WhT stored bf16 as [bt][o][j]  (MFMA B-operand friendly layout).
// grid (2, 96), 256 threads; thread = one node n.
// ---------------------------------------------------------------------------
__global__ __launch_bounds__(256) void gat_prep(
    const float* __restrict__ input,   // (8,64,12,512)
    const float* __restrict__ W,       // (64,64)
    const float* __restrict__ Avec,    // (128,1)
    u16*   __restrict__ whT,           // (96,64,512) bf16
    float* __restrict__ f1w,           // (96,512)
    float* __restrict__ f2w)           // (96,512)
{
  __shared__ float Wl[64*64];
  __shared__ float Al[128];
  const int tid = threadIdx.x;
  const int bt  = blockIdx.y;
  const int b   = bt / 12, t = bt % 12;
  const int n   = blockIdx.x * 256 + tid;

  {
    const fx4* src = (const fx4*)W;
    fx4* dst = (fx4*)Wl;
    #pragma unroll
    for (int i = 0; i < 4; ++i) dst[tid + 256*i] = src[tid + 256*i];
    if (tid < 32) ((fx4*)Al)[tid] = ((const fx4*)Avec)[tid];
  }
  __syncthreads();

  // x[b, f, t, n], stride between f = 12*512 = 6144
  const float* xp = input + ((size_t)b*64*12 + t) * 512 + n;

  fx4 acc[16];
  #pragma unroll
  for (int i = 0; i < 16; ++i) acc[i] = (fx4){0.f,0.f,0.f,0.f};

  #pragma unroll 8
  for (int f = 0; f < 64; ++f) {
    float xv = xp[(size_t)f * 6144];
    const fx4* wr = (const fx4*)(Wl + f*64);
    #pragma unroll
    for (int o4 = 0; o4 < 16; ++o4) acc[o4] += xv * wr[o4];
  }

  float s1 = 0.f, s2 = 0.f;
  #pragma unroll
  for (int o4 = 0; o4 < 16; ++o4) {
    fx4 v  = acc[o4];
    fx4 w1 = ((const fx4*)Al)[o4];
    fx4 w2 = ((const fx4*)Al)[o4 + 16];
    s1 += v[0]*w1[0] + v[1]*w1[1] + v[2]*w1[2] + v[3]*w1[3];
    s2 += v[0]*w2[0] + v[1]*w2[1] + v[2]*w2[2] + v[3]*w2[3];
  }
  f1w[bt*512 + n] = s1;
  f2w[bt*512 + n] = s2;

  u16* wp = whT + (size_t)bt*64*512 + n;
  #pragma unroll
  for (int o4 = 0; o4 < 16; ++o4) {
    #pragma unroll
    for (int c = 0; c < 4; ++c)
      wp[(size_t)(o4*4 + c) * 512] = f2bf(acc[o4][c]);
  }
}

// ---------------------------------------------------------------------------
// Kernel 2: masked softmax (phase A, TRUE per-row max; deferred norm) +
// PV via MFMA (phase B) + normalize + ELU.
// grid (32, 96), 256 threads (4 waves). 16 rows per block, 4 rows per wave.
//
// Exact numerics: per-row max via one 6-step butterfly per row (the only
// in-loop cross-lane chain); sum reduction hoisted after the loop as 4
// ILP-overlapped butterflies; normalization deferred past the linear MFMA.
// With true max, the argmax entry contributes exp(0)=1 -> sum >= 1 -> no
// divide-by-zero possible (the R2 NaN).
// ---------------------------------------------------------------------------
__global__ __launch_bounds__(256) void gat_attn(
    const int*   __restrict__ adj,   // (96,512,512)
    const u16*   __restrict__ whT,   // (96,64,512) bf16
    const float* __restrict__ f1w,
    const float* __restrict__ f2w,
    float*       __restrict__ out)   // (96,512,64)
{
  __shared__ float f2l[512];
  __shared__ float f1l[16];
  __shared__ float sums[16];
  __shared__ u16   attnl[16*512];    // unnormalized p, bf16, XOR-swizzled

  const int tid = threadIdx.x;
  const int l   = tid & 63;
  const int w   = tid >> 6;
  const int bt  = blockIdx.y;
  const int it  = blockIdx.x;

  ((float2*)f2l)[tid] = ((const float2*)(f2w + bt*512))[tid];
  if (tid < 16) f1l[tid] = f1w[bt*512 + it*16 + tid];
  __syncthreads();

  // ---------------- phase A: p = exp(e - rowmax), unnormalized ------------
  const int R0     = w * 4;
  const int row_g0 = it*16 + R0;
  const int4* adj4 = (const int4*)(adj + (size_t)bt*512*512);

  int4 pre[4][2];                    // this wave's 4 rows, loaded upfront
  #pragma unroll
  for (int p = 0; p < 4; ++p) {
    const int4* ar = adj4 + (size_t)(row_g0 + p) * 128;
    pre[p][0] = ar[l];
    pre[p][1] = ar[64 + l];
  }

  const fx4 f20 = ((const fx4*)f2l)[l];        // j = 4l .. 4l+3
  const fx4 f21 = ((const fx4*)f2l)[64 + l];   // j = 256+4l ..

  float psum[4];
  #pragma unroll
  for (int r = 0; r < 4; ++r) {
    const int4 c0 = pre[r][0];
    const int4 c1 = pre[r][1];
    const float f1v = f1l[R0 + r];

    float e[8], m = NEG_INF_F;
#define GAT_E(idx, cc, ff) { float s = f1v + (ff); float lr = s > 0.f ? s : 0.2f*s; \
                             e[idx] = ((cc) > 0) ? lr : NEG_INF_F; m = fmaxf(m, e[idx]); }
    GAT_E(0, c0.x, f20[0]) GAT_E(1, c0.y, f20[1]) GAT_E(2, c0.z, f20[2]) GAT_E(3, c0.w, f20[3])
    GAT_E(4, c1.x, f21[0]) GAT_E(5, c1.y, f21[1]) GAT_E(6, c1.z, f21[2]) GAT_E(7, c1.w, f21[3])
#undef GAT_E
    #pragma unroll
    for (int off = 32; off >= 1; off >>= 1) m = fmaxf(m, __shfl_xor(m, off));

    float p[8], sum = 0.f;
    #pragma unroll
    for (int i = 0; i < 8; ++i) { p[i] = __expf(e[i] - m); sum += p[i]; }
    psum[r] = sum;

    const int rowR = R0 + r;
    const unsigned swz = (unsigned)((rowR & 7) << 4);
    char* base = (char*)attnl + rowR * 1024;
    ushort4 pk0, pk1;
    pk0.x = f2bf(p[0]); pk0.y = f2bf(p[1]); pk0.z = f2bf(p[2]); pk0.w = f2bf(p[3]);
    pk1.x = f2bf(p[4]); pk1.y = f2bf(p[5]); pk1.z = f2bf(p[6]); pk1.w = f2bf(p[7]);
    *(ushort4*)(base + (((unsigned)(      8*l)) ^ swz)) = pk0;
    *(ushort4*)(base + (((unsigned)(512 + 8*l)) ^ swz)) = pk1;
  }

  // 4 independent sum-butterflies (ILP-overlapped), then lane0 publishes
  #pragma unroll
  for (int r = 0; r < 4; ++r) {
    #pragma unroll
    for (int off = 32; off >= 1; off >>= 1) psum[r] += __shfl_xor(psum[r], off);
  }
  if (l == 0) {
    #pragma unroll
    for (int r = 0; r < 4; ++r) sums[R0 + r] = psum[r];
  }

  __syncthreads();

  // ---------------- phase B: h = p @ Wh via MFMA; normalize + ELU ---------
  const int r = l & 15, q = l >> 4;
  const unsigned swzB = (unsigned)((r & 7) << 4);
  const char* aBase = (const char*)attnl + r * 1024;        // A row = l&15
  const u16*  wb    = whT + (size_t)bt*64*512 + (size_t)(w*16 + r)*512;
  fx4 acc = {0,0,0,0};

  #pragma unroll
  for (int jt = 0; jt < 512; jt += 32) {
    i16x8 af = *(const i16x8*)(aBase + (((unsigned)(jt*2 + q*16)) ^ swzB));
    i16x8 bf = *(const i16x8*)(wb + jt + 8*q);
    acc = __builtin_amdgcn_mfma_f32_16x16x32_bf16(af, bf, acc, 0, 0, 0);
  }

  // C/D layout: col = l&15 (=o within tile), row = q*4 + rr
  float* op = out + ((size_t)bt*512 + it*16) * 64;
  #pragma unroll
  for (int rr = 0; rr < 4; ++rr) {
    const float rs = 1.0f / sums[q*4 + rr];
    float v = acc[rr] * rs;
    v = v > 0.f ? v : expm1f(v);
    op[(q*4 + rr)*64 + w*16 + r] = v;
  }
}

// ---------------------------------------------------------------------------
extern "C" void kernel_launch(void* const* d_in, const int* in_sizes, int n_in,
                              void* d_out, int out_size, void* d_ws, size_t ws_size,
                              hipStream_t stream) {
  const float* input = (const float*)d_in[0];   // (8,64,12,512) f32
  const int*   adj   = (const int*)  d_in[1];   // (8,12,512,512) i32
  const float* W     = (const float*)d_in[2];   // (64,64) f32
  const float* Avec  = (const float*)d_in[3];   // (128,1) f32
  float* out = (float*)d_out;

  // workspace layout: whT bf16 (6,291,456 B) | f1 (196,608 B) | f2 (196,608 B)
  char* ws = (char*)d_ws;
  u16*   whT = (u16*)ws;
  float* f1w = (float*)(ws + 6291456);
  float* f2w = (float*)(ws + 6291456 + 196608);

  gat_prep<<<dim3(2, 96), 256, 0, stream>>>(input, W, Avec, whT, f1w, f2w);
  gat_attn<<<dim3(32, 96), 256, 0, stream>>>(adj, whT, f1w, f2w, out);
}